// Round 10
// baseline (398.225 us; speedup 1.0000x reference)
//
#include <hip/hip_runtime.h>
#include <hip/hip_bf16.h>

#define N_NODES 100000
#define N_EDGES 1000000
#define DIM 64
#define N_GRAPHS 256
#define OUT_DIM 10
#define BN_EPS 1e-5f

#define POOL_BLOCKS 512                      // 2048 waves
#define LAYER_BLOCKS ((N_NODES + 63) / 64)   // 1563
#define PAD 24                               // slots per node; P(deg>24)~4e-5
#define SPILL_CAP 8192
#define NPART 8                              // dst partitions (one per XCD)
#define PART_SZ ((N_NODES + NPART - 1) / NPART)   // 12500

typedef __bf16 bf16x8 __attribute__((ext_vector_type(8)));
typedef float f32x4 __attribute__((ext_vector_type(4)));

// ---------------------------------------------------------------------------
// Edge fill, XCD-partitioned (see R6): 8 block-replicas per 256-edge tile;
// replica part=blockIdx&7 handles only dst in its 12500-node range so each
// ESRC range is written by ~one XCD's L2 (kills cross-XCD dirty-line dup).
// ---------------------------------------------------------------------------
__global__ __launch_bounds__(256) void fill_kernel(
    const int* __restrict__ ei, int* __restrict__ deg,
    int* __restrict__ esrc, int* __restrict__ nspill, int* __restrict__ spill)
{
    const int part = blockIdx.x & (NPART - 1);
    const int e = (blockIdx.x >> 3) * 256 + threadIdx.x;
    if (e >= N_EDGES) return;
    int dst = ei[N_EDGES + e];
    int lo = part * PART_SZ;
    if (dst < lo || dst >= lo + PART_SZ) return;
    int src = ei[e];
    int pos = atomicAdd(&deg[dst], 1);
    if (pos < PAD) {
        esrc[dst * PAD + pos] = src;
    } else {
        int sp = atomicAdd(nspill, 1);
        if (sp < SPILL_CAP) { spill[2 * sp] = dst; spill[2 * sp + 1] = src; }
    }
}

// ---------------------------------------------------------------------------
// x0 -> bf16 copy (gather payload halving). 4 elems/thread.
// ---------------------------------------------------------------------------
__global__ __launch_bounds__(256) void xcast_kernel(
    const float4* __restrict__ xin, ushort4* __restrict__ xout)
{
    int t = blockIdx.x * 256 + threadIdx.x;
    if (t >= N_NODES * 16) return;
    float4 v = xin[t];
    ushort4 o;
    o.x = __builtin_bit_cast(unsigned short, (__bf16)v.x);
    o.y = __builtin_bit_cast(unsigned short, (__bf16)v.y);
    o.z = __builtin_bit_cast(unsigned short, (__bf16)v.z);
    o.w = __builtin_bit_cast(unsigned short, (__bf16)v.w);
    xout[t] = o;
}

// ---------------------------------------------------------------------------
// BN prep: per-dim affine from accumulated sum/sumsq.
// sc[0..63] = scale, sc[64..127] = shift.  y = relu(scale*v + shift)
// ---------------------------------------------------------------------------
__global__ __launch_bounds__(64) void bnprep_kernel(
    const float* __restrict__ sums, const float* __restrict__ gamma,
    const float* __restrict__ beta, float* __restrict__ sc)
{
    int d = threadIdx.x;
    const float inv_n = 1.0f / (float)N_NODES;
    float mean = sums[d] * inv_n;
    float m2 = sums[64 + d] * inv_n;
    float var = m2 - mean * mean;
    float scale = gamma[d] * rsqrtf(var + BN_EPS);
    sc[d] = scale;
    sc[64 + d] = fmaf(-mean, scale, beta[d]);
}

// ---------------------------------------------------------------------------
// Weight prep: split each 64x64 fp32 W into bf16 hi/lo, stored in MFMA
// B-fragment order: blob[(kstep*4+ntile)*64 + lane][j]; hi at +0, lo at +4096.
// ---------------------------------------------------------------------------
__global__ __launch_bounds__(256) void wprep_kernel(
    const float* __restrict__ w1, const float* __restrict__ w2,
    __bf16* __restrict__ wf)
{
    int L = blockIdx.x >> 1, mat = blockIdx.x & 1;
    const float* w = (mat ? w2 : w1) + L * 4096;
    __bf16* dst = wf + blockIdx.x * 8192;
#pragma unroll
    for (int r = 0; r < 2; ++r) {
        int idx = threadIdx.x + 256 * r;          // (kstep*4+nt)*64 + lane
        int lane = idx & 63;
        int kt = idx >> 6;
        int kstep = kt >> 2, nt = kt & 3;
        int n = nt * 16 + (lane & 15);
        int kbase = kstep * 32 + (lane >> 4) * 8;
#pragma unroll
        for (int j = 0; j < 8; ++j) {
            float v = w[(kbase + j) * 64 + n];
            __bf16 hi = (__bf16)v;
            dst[idx * 8 + j] = hi;
            dst[4096 + idx * 8 + j] = (__bf16)(v - (float)hi);
        }
    }
}

// ---------------------------------------------------------------------------
// FUSED GIN layer (R9): gather + spill + (1+eps)*self + 2-GEMM MLP + BN.
// vs R8: neighbor gather reads a bf16 copy of the layer input (128 B/row
// instead of 256 B) — the layer was fabric-BW-bound (1.85 TB/s, FETCH 124 MB)
// so halving gather bytes is the lever. Self term + h2 output stay fp32;
// epilogue additionally emits the bf16 copy for the next layer (ping-pong).
// Single per-wave LDS tile (aliased h/h1, race-free by wave lockstep);
// deg prefetch + readlane; esrc rows software-pipelined one node ahead.
// ---------------------------------------------------------------------------
template <bool BN>
__global__ __launch_bounds__(256) void layer_kernel(
    const float* __restrict__ x, const unsigned short* __restrict__ xb,
    const float* __restrict__ sc,
    const int* __restrict__ deg, const int* __restrict__ esrc,
    const int* __restrict__ nspill, const int* __restrict__ spill,
    float* __restrict__ h2out, unsigned short* __restrict__ xbout,
    const __bf16* __restrict__ wf1, const __bf16* __restrict__ wf2,
    const float* __restrict__ b1, const float* __restrict__ b2,
    const float* __restrict__ eps_all, int layer,
    float* __restrict__ sums)
{
    __shared__ __attribute__((aligned(16))) unsigned tile[4][16][68];
    __shared__ float bnacc[128];

    const int tid = threadIdx.x;
    const int lane = tid & 63;
    const int wv = tid >> 6;
    const int q = lane >> 4;      // quad
    const int r = lane & 15;      // row-in-quad / col
    const int node0 = blockIdx.x * 64 + wv * 16;
    const bool active = node0 < N_NODES;   // 16-node tiles never straddle N

    if (tid < 128) bnacc[tid] = 0.0f;

    f32x4 acc[4];
    float bs[4], bq[4];
#pragma unroll
    for (int nt = 0; nt < 4; ++nt) {
        acc[nt] = (f32x4){0.f, 0.f, 0.f, 0.f};
        bs[nt] = 0.0f; bq[nt] = 0.0f;
    }

    float scale = 1.0f, shift = 0.0f;
    if (BN) { scale = sc[lane]; shift = sc[64 + lane]; }

    if (active) {
        const float epsv = 1.0f + eps_all[layer];

        // ---- Phase A: gather + self, lane = dim ----
        int dvec = 0;
        if (lane < 16) dvec = deg[node0 + lane];
        uint4 nf0, nf1, nf2;
        {
            const uint4* ip = (const uint4*)(esrc + (size_t)node0 * PAD);
            nf0 = ip[0]; nf1 = ip[1]; nf2 = ip[2];
        }
        for (int i = 0; i < 16; ++i) {
            const uint4 c0 = nf0, c1 = nf1, c2 = nf2;
            if (i < 15) {   // issue next node's idx loads before consuming
                const uint4* ip = (const uint4*)(esrc + (size_t)(node0 + i + 1) * PAD);
                nf0 = ip[0]; nf1 = ip[1]; nf2 = ip[2];
            }
            const int n = node0 + i;
            const int dfull = __builtin_amdgcn_readlane(dvec, i);  // wave-uniform
            const int d = min(dfull, PAD);

            float xv = x[(size_t)n * 64 + lane];       // fp32 self term
            if (BN) xv = fmaxf(fmaf(xv, scale, shift), 0.0f);
            float hval = epsv * xv;

            {   // chunk 0: idx already in registers; bf16 neighbor rows
                unsigned idx[12] = {c0.x, c0.y, c0.z, c0.w, c1.x, c1.y,
                                    c1.z, c1.w, c2.x, c2.y, c2.z, c2.w};
                unsigned short u[12];
#pragma unroll
                for (int j = 0; j < 12; ++j) {
                    unsigned s = idx[j];
                    s = (s < (unsigned)N_NODES) ? s : 0u;   // garbage past d
                    u[j] = xb[(size_t)s * 64 + lane];
                }
#pragma unroll
                for (int j = 0; j < 12; ++j) {
                    float t = (float)__builtin_bit_cast(__bf16, u[j]);
                    if (BN) t = fmaxf(fmaf(t, scale, shift), 0.0f);
                    hval += (j < d) ? t : 0.0f;
                }
            }
            if (d > 12) {   // wave-uniform branch, ~25% of nodes
                const int* ep = esrc + (size_t)n * PAD + 12;
                unsigned short u[12];
#pragma unroll
                for (int j = 0; j < 12; ++j) {
                    unsigned s = (unsigned)ep[j];
                    s = (s < (unsigned)N_NODES) ? s : 0u;
                    u[j] = xb[(size_t)s * 64 + lane];
                }
#pragma unroll
                for (int j = 0; j < 12; ++j) {
                    float t = (float)__builtin_bit_cast(__bf16, u[j]);
                    if (BN) t = fmaxf(fmaf(t, scale, shift), 0.0f);
                    hval += (12 + j < d) ? t : 0.0f;
                }
            }
            if (dfull > PAD) {   // ultra-rare: scan tiny spill list
                int ns = min(*nspill, SPILL_CAP);
                for (int e = 0; e < ns; ++e) {
                    if (spill[2 * e] == n) {
                        float t = (float)__builtin_bit_cast(
                            __bf16, xb[(size_t)spill[2 * e + 1] * 64 + lane]);
                        if (BN) t = fmaxf(fmaf(t, scale, shift), 0.0f);
                        hval += t;
                    }
                }
            }
            __bf16 hi = (__bf16)hval;
            __bf16 lo = (__bf16)(hval - (float)hi);
            tile[wv][i][lane] = ((unsigned)__builtin_bit_cast(unsigned short, hi) << 16)
                              | (unsigned)__builtin_bit_cast(unsigned short, lo);
        }

        // ---- Phase B1: pull BOTH ksteps' A-frags into regs, then GEMM1 ----
        uint4 f0 = *(const uint4*)&tile[wv][r][q * 8];
        uint4 f1 = *(const uint4*)&tile[wv][r][q * 8 + 4];
        uint4 f2 = *(const uint4*)&tile[wv][r][32 + q * 8];
        uint4 f3 = *(const uint4*)&tile[wv][r][32 + q * 8 + 4];
#pragma unroll
        for (int kstep = 0; kstep < 2; ++kstep) {
            uint4 p0 = kstep ? f2 : f0;
            uint4 p1 = kstep ? f3 : f1;
            unsigned pk[8] = {p0.x, p0.y, p0.z, p0.w, p1.x, p1.y, p1.z, p1.w};
            bf16x8 ahi, alo;
#pragma unroll
            for (int j = 0; j < 8; ++j) {
                ahi[j] = __builtin_bit_cast(__bf16, (unsigned short)(pk[j] >> 16));
                alo[j] = __builtin_bit_cast(__bf16, (unsigned short)(pk[j] & 0xffffu));
            }
#pragma unroll
            for (int nt = 0; nt < 4; ++nt) {
                const __bf16* bp = wf1 + ((kstep * 4 + nt) * 64 + lane) * 8;
                bf16x8 bhi = *(const bf16x8*)bp;
                bf16x8 blo = *(const bf16x8*)(bp + 4096);
                acc[nt] = __builtin_amdgcn_mfma_f32_16x16x32_bf16(ahi, bhi, acc[nt], 0, 0, 0);
                acc[nt] = __builtin_amdgcn_mfma_f32_16x16x32_bf16(alo, bhi, acc[nt], 0, 0, 0);
                acc[nt] = __builtin_amdgcn_mfma_f32_16x16x32_bf16(ahi, blo, acc[nt], 0, 0, 0);
            }
        }
        // ---- bias + relu, repack h1 (hi|lo) into the SAME tile ----
#pragma unroll
        for (int nt = 0; nt < 4; ++nt) {
            float b1v = b1[nt * 16 + r];
#pragma unroll
            for (int reg = 0; reg < 4; ++reg) {
                float v = fmaxf(acc[nt][reg] + b1v, 0.0f);
                __bf16 hi = (__bf16)v;
                __bf16 lo = (__bf16)(v - (float)hi);
                unsigned pk = ((unsigned)__builtin_bit_cast(unsigned short, hi) << 16)
                            | (unsigned)__builtin_bit_cast(unsigned short, lo);
                tile[wv][q * 4 + reg][nt * 16 + r] = pk;
            }
            acc[nt] = (f32x4){0.f, 0.f, 0.f, 0.f};
        }
        // ---- Phase B2: GEMM2 from tile ----
#pragma unroll
        for (int kstep = 0; kstep < 2; ++kstep) {
            uint4 p0 = *(const uint4*)&tile[wv][r][kstep * 32 + q * 8];
            uint4 p1 = *(const uint4*)&tile[wv][r][kstep * 32 + q * 8 + 4];
            unsigned pk[8] = {p0.x, p0.y, p0.z, p0.w, p1.x, p1.y, p1.z, p1.w};
            bf16x8 ahi, alo;
#pragma unroll
            for (int j = 0; j < 8; ++j) {
                ahi[j] = __builtin_bit_cast(__bf16, (unsigned short)(pk[j] >> 16));
                alo[j] = __builtin_bit_cast(__bf16, (unsigned short)(pk[j] & 0xffffu));
            }
#pragma unroll
            for (int nt = 0; nt < 4; ++nt) {
                const __bf16* bp = wf2 + ((kstep * 4 + nt) * 64 + lane) * 8;
                bf16x8 bhi = *(const bf16x8*)bp;
                bf16x8 blo = *(const bf16x8*)(bp + 4096);
                acc[nt] = __builtin_amdgcn_mfma_f32_16x16x32_bf16(ahi, bhi, acc[nt], 0, 0, 0);
                acc[nt] = __builtin_amdgcn_mfma_f32_16x16x32_bf16(alo, bhi, acc[nt], 0, 0, 0);
                acc[nt] = __builtin_amdgcn_mfma_f32_16x16x32_bf16(ahi, blo, acc[nt], 0, 0, 0);
            }
        }
        // ---- epilogue: bias + relu, store fp32 + bf16 copy, BN partials ----
#pragma unroll
        for (int nt = 0; nt < 4; ++nt) {
            float b2v = b2[nt * 16 + r];
#pragma unroll
            for (int reg = 0; reg < 4; ++reg) {
                float v = fmaxf(acc[nt][reg] + b2v, 0.0f);
                size_t oi = (size_t)(node0 + q * 4 + reg) * 64 + nt * 16 + r;
                h2out[oi] = v;
                xbout[oi] = __builtin_bit_cast(unsigned short, (__bf16)v);
                bs[nt] += v;
                bq[nt] = fmaf(v, v, bq[nt]);
            }
        }
    }
    // ---- BN reduction: quads -> wave (shfl), waves -> block (LDS atomics) ----
    __syncthreads();                       // bnacc init visible to all waves
#pragma unroll
    for (int nt = 0; nt < 4; ++nt) {
        float s = bs[nt];
        s += __shfl_xor(s, 16);
        s += __shfl_xor(s, 32);
        float ss = bq[nt];
        ss += __shfl_xor(ss, 16);
        ss += __shfl_xor(ss, 32);
        if (q == 0) {
            atomicAdd(&bnacc[nt * 16 + r], s);
            atomicAdd(&bnacc[64 + nt * 16 + r], ss);
        }
    }
    __syncthreads();
    if (tid < 128) unsafeAtomicAdd(&sums[tid], bnacc[tid]);
}

// ---------------------------------------------------------------------------
// Segmented global mean pool (batch sorted): register-accumulate per graph,
// one atomic flush per boundary. Applies last layer's BN affine+relu on load.
// ---------------------------------------------------------------------------
__global__ __launch_bounds__(256) void pool_kernel(
    const float* __restrict__ h2, const float* __restrict__ sc,
    const int* __restrict__ batch,
    float* __restrict__ pooled, float* __restrict__ counts)
{
    const int lane = threadIdx.x & 63;
    const int w = blockIdx.x * 4 + (threadIdx.x >> 6);
    const int nw = POOL_BLOCKS * 4;
    const int npw = (N_NODES + nw - 1) / nw;
    int n0 = w * npw;
    if (n0 >= N_NODES) return;
    int n1 = n0 + npw;
    if (n1 > N_NODES) n1 = N_NODES;

    const float scale = sc[lane];
    const float shift = sc[64 + lane];

    int cur = batch[n0];
    float acc = 0.0f, cnt = 0.0f;
    for (int n = n0; n < n1; ++n) {
        int g = batch[n];                       // wave-uniform
        if (g != cur) {
            unsafeAtomicAdd(&pooled[cur * 64 + lane], acc);
            if (lane == 0) unsafeAtomicAdd(&counts[cur], cnt);
            acc = 0.0f; cnt = 0.0f; cur = g;
        }
        float v = h2[(size_t)n * 64 + lane];
        v = fmaxf(fmaf(v, scale, shift), 0.0f);
        acc += v;
        cnt += 1.0f;
    }
    unsafeAtomicAdd(&pooled[cur * 64 + lane], acc);
    if (lane == 0) unsafeAtomicAdd(&counts[cur], cnt);
}

// ---------------------------------------------------------------------------
// Final linear.
// ---------------------------------------------------------------------------
__global__ __launch_bounds__(256) void final_kernel(
    const float* __restrict__ pooled, const float* __restrict__ counts,
    const float* __restrict__ lin_w, const float* __restrict__ lin_b,
    float* __restrict__ out)
{
    int t = blockIdx.x * 256 + threadIdx.x;
    if (t >= N_GRAPHS * OUT_DIM) return;
    int g = t / OUT_DIM;
    int o = t - g * OUT_DIM;
    float acc = 0.0f;
#pragma unroll 8
    for (int d = 0; d < 64; ++d)
        acc = fmaf(pooled[g * 64 + d], lin_w[d * OUT_DIM + o], acc);
    float c = fmaxf(counts[g], 1.0f);
    out[t] = acc / c + lin_b[o];
}

extern "C" void kernel_launch(void* const* d_in, const int* in_sizes, int n_in,
                              void* d_out, int out_size, void* d_ws, size_t ws_size,
                              hipStream_t stream)
{
    const float* x0    = (const float*)d_in[0];
    const int*   ei    = (const int*)d_in[1];
    const int*   batch = (const int*)d_in[2];
    const float* w1    = (const float*)d_in[3];
    const float* b1    = (const float*)d_in[4];
    const float* w2    = (const float*)d_in[5];
    const float* b2    = (const float*)d_in[6];
    const float* gamma = (const float*)d_in[7];
    const float* beta  = (const float*)d_in[8];
    const float* eps_g = (const float*)d_in[9];
    const float* lin_w = (const float*)d_in[10];
    const float* lin_b = (const float*)d_in[11];
    float* out = (float*)d_out;

    // Workspace layout: zeroed region (SUMS..NSPILL) contiguous.
    float* ws   = (float*)d_ws;
    float* A    = ws;                                // h2 ping, 6.4M floats
    float* B    = ws + (size_t)N_NODES * 64;         // h2 pong, 6.4M floats
    float* SUMS = ws + (size_t)2 * N_NODES * 64;     // 3*128   [zeroed]
    float* POOL = SUMS + 384;                        // 16384   [zeroed]
    float* CNT  = POOL + N_GRAPHS * 64;              // 256     [zeroed]
    int*   DEG    = (int*)(CNT + N_GRAPHS);          // 100000  [zeroed]
    int*   NSPILL = DEG + N_NODES;                   // 16      [zeroed]
    float* SC   = (float*)(NSPILL + 16);             // 3*128
    __bf16* WF  = (__bf16*)(SC + 384);               // 6*8192 bf16 = 96 KB
    int*   SPILL  = (int*)(WF + 6 * 8192);           // 2*SPILL_CAP
    int*   ESRC   = SPILL + 2 * SPILL_CAP;           // 24*N = 9.6 MB
    unsigned short* XP = (unsigned short*)(ESRC + (size_t)N_NODES * PAD); // bf16 ping, 12.8 MB
    unsigned short* XQ = XP + (size_t)N_NODES * 64;                       // bf16 pong, 12.8 MB
    unsigned short* XR = XQ + (size_t)N_NODES * 64;                       // bf16 (L2 out, unused), 12.8 MB

    const size_t zero_bytes = (384 + N_GRAPHS * 64 + N_GRAPHS) * sizeof(float)
                            + (N_NODES + 16) * sizeof(int);
    const int fill_blocks = ((N_EDGES + 255) / 256) * NPART;  // 31256
    const int elem_blocks = (N_NODES * 16 + 255) / 256;       // 6250

    // ---- once per call: zeroing, weight fragments, x0 bf16 cast, edge fill ----
    hipMemsetAsync(SUMS, 0, zero_bytes, stream);
    wprep_kernel<<<6, 256, 0, stream>>>(w1, w2, WF);
    xcast_kernel<<<elem_blocks, 256, 0, stream>>>((const float4*)x0, (ushort4*)XP);
    fill_kernel<<<fill_blocks, 256, 0, stream>>>(ei, DEG, ESRC, NSPILL, SPILL);

    // ---- 3 fused GIN layers (BN of layer L folded into layer L+1) ----
    layer_kernel<false><<<LAYER_BLOCKS, 256, 0, stream>>>(
        x0, XP, nullptr, DEG, ESRC, NSPILL, SPILL, A, XQ,
        WF, WF + 8192, b1, b2, eps_g, 0, SUMS);
    bnprep_kernel<<<1, 64, 0, stream>>>(SUMS, gamma, beta, SC);

    layer_kernel<true><<<LAYER_BLOCKS, 256, 0, stream>>>(
        A, XQ, SC, DEG, ESRC, NSPILL, SPILL, B, XP,
        WF + 16384, WF + 24576, b1 + 64, b2 + 64, eps_g, 1, SUMS + 128);
    bnprep_kernel<<<1, 64, 0, stream>>>(SUMS + 128, gamma + 64, beta + 64, SC + 128);

    layer_kernel<true><<<LAYER_BLOCKS, 256, 0, stream>>>(
        B, XP, SC + 128, DEG, ESRC, NSPILL, SPILL, A, XR,
        WF + 32768, WF + 40960, b1 + 128, b2 + 128, eps_g, 2, SUMS + 256);
    bnprep_kernel<<<1, 64, 0, stream>>>(SUMS + 256, gamma + 128, beta + 128, SC + 256);

    // ---- segmented pool (applies bn of L2) + linear ----
    pool_kernel<<<POOL_BLOCKS, 256, 0, stream>>>(A, SC + 256, batch, POOL, CNT);
    final_kernel<<<(N_GRAPHS * OUT_DIM + 255) / 256, 256, 0, stream>>>(
        POOL, CNT, lin_w, lin_b, out);
}